// Round 2
// baseline (266.767 us; speedup 1.0000x reference)
//
#include <hip/hip_runtime.h>
#include <hip/hip_fp16.h>

#define B_ROWS 2048
#define C_COLS 65536
#define D_DIM  256
#define N_NEG  50
#define NTILES (C_COLS / 128)   // 512 column tiles

typedef __attribute__((ext_vector_type(8))) short short8;
typedef __attribute__((ext_vector_type(4))) float floatx4;
typedef __fp16 f16x2 __attribute__((ext_vector_type(2)));

__device__ __forceinline__ ushort f2bf(float f) {
  unsigned u = __float_as_uint(f);
  unsigned r = (u + 0x7FFFu + ((u >> 16) & 1u)) >> 16;  // RNE
  return (ushort)r;
}

__device__ __forceinline__ uint hmax2(uint a, uint b) {
  union { uint u; f16x2 h; } x, y, r;
  x.u = a; y.u = b;
  r.h = __builtin_elementwise_max(x.h, y.h);
  return r.u;
}

// ---------------- fp32 -> bf16 convert, K-block XOR swizzle (f only now) ----
__global__ void cvt_swz(const float* __restrict__ in, ushort* __restrict__ out, int n8) {
  int i = blockIdx.x * blockDim.x + threadIdx.x;
  if (i >= n8) return;
  int row = i >> 5;
  int ka  = i & 31;
  int ktile = ka >> 3, kb = ka & 7;
  const float4* src = (const float4*)(in + (size_t)i * 8);
  float4 a = src[0], b = src[1];
  ushort4 o0, o1;
  o0.x = f2bf(a.x); o0.y = f2bf(a.y); o0.z = f2bf(a.z); o0.w = f2bf(a.w);
  o1.x = f2bf(b.x); o1.y = f2bf(b.y); o1.z = f2bf(b.z); o1.w = f2bf(b.w);
  ushort* dst = out + (size_t)row * D_DIM + ktile * 64 + ((kb ^ (row & 7)) << 3);
  ((ushort4*)dst)[0] = o0;
  ((ushort4*)dst)[1] = o1;
}

__device__ __forceinline__ void async16(const void* g, void* l) {
  __builtin_amdgcn_global_load_lds((const __attribute__((address_space(1))) void*)g,
                                   (__attribute__((address_space(3))) void*)l,
                                   16, 0, 0);
}

// ---------------- fused GEMM (D[n][m]) + fp32->bf16 cen convert + 16:1 group-max ----
// Grid (16 slabs, 512 tiles); XCD-chunked swizzle: each XCD owns 64 consecutive tiles
// (all 16 slabs) -> each cen fp32 tile converted/read within one XCD's L2.
// cand[row][tile][g] = fp16 max of cols [tile*128 + g*16, +16), label col masked.
__global__ void gemm_reduce(const ushort* __restrict__ fb,
                            const float* __restrict__ cen,
                            const int* __restrict__ label,
                            ushort* __restrict__ cand) {
  __shared__ __align__(16) ushort Cs[128 * 64];   // cen bf16 [128][64], swizzled kblks
  __shared__ __align__(16) ushort Fs[128 * 64];   // f   bf16 [128][64], swizzled kblks
  __shared__ __align__(16) ushort gm[128][8];     // fp16 group-max [m][group]
  __shared__ int labLDS[128];

  const int tid = threadIdx.x, wave = tid >> 6, lane = tid & 63;
  const int l = lane & 15, q = lane >> 4;

  // T1: bijective XCD-chunk remap (8192 blocks, 8 XCDs, 1024 each; slab-fastest inside)
  const int lin = blockIdx.y * 16 + blockIdx.x;
  const int lg  = (lin & 7) * 1024 + (lin >> 3);
  const int m0 = (lg & 15) << 7;
  const int bxTile = lg >> 4;
  const int n0 = bxTile << 7;
  if (tid < 128) labLDS[tid] = label[m0 + tid];

  floatx4 acc[4][4] = {};               // [i: n-block][j: m-block]
  const int wn = (wave >> 1) * 64, wm = (wave & 1) * 64;

  for (int kt = 0; kt < D_DIM / 64; ++kt) {
#pragma unroll
    for (int r = 0; r < 4; ++r) {
      int idx = r * 2048 + wave * 512 + lane * 8;
      int row = idx >> 6, kk = idx & 63;
      async16(fb + (size_t)(m0 + row) * D_DIM + kt * 64 + kk, Fs + r * 2048 + wave * 512);
    }
    // fused cen fp32 load (8 in flight) -> bf16 RNE -> swizzled LDS store
    float4 ra[4], rb[4];
#pragma unroll
    for (int g = 0; g < 4; ++g) {
      int e = (tid + g * 256) * 8;
      const float* gp = cen + (size_t)(n0 + (e >> 6)) * D_DIM + kt * 64 + (e & 63);
      ra[g] = *(const float4*)gp;
      rb[g] = *(const float4*)(gp + 4);
    }
#pragma unroll
    for (int g = 0; g < 4; ++g) {
      int e = (tid + g * 256) * 8;
      int row = e >> 6, kblk = (e >> 3) & 7;
      uint4 o;
      o.x = (uint)f2bf(ra[g].x) | ((uint)f2bf(ra[g].y) << 16);
      o.y = (uint)f2bf(ra[g].z) | ((uint)f2bf(ra[g].w) << 16);
      o.z = (uint)f2bf(rb[g].x) | ((uint)f2bf(rb[g].y) << 16);
      o.w = (uint)f2bf(rb[g].z) | ((uint)f2bf(rb[g].w) << 16);
      *(uint4*)(Cs + (row << 6) + ((kblk ^ (row & 7)) << 3)) = o;
    }
    __syncthreads();

#pragma unroll
    for (int ks = 0; ks < 2; ++ks) {
      short8 a[4], b[4];
#pragma unroll
      for (int i = 0; i < 4; ++i) {
        int swz = ((4 * ks + q) ^ (l & 7)) << 3;
        a[i] = *(const short8*)(Cs + ((wn + i * 16 + l) << 6) + swz);
        b[i] = *(const short8*)(Fs + ((wm + i * 16 + l) << 6) + swz);
      }
#pragma unroll
      for (int i = 0; i < 4; ++i)
#pragma unroll
        for (int j = 0; j < 4; ++j)
          acc[i][j] = __builtin_amdgcn_mfma_f32_16x16x32_bf16(a[i], b[j], acc[i][j], 0, 0, 0);
    }
    __syncthreads();
  }

  // ---- epilogue: in-register label mask + 16:1 group-max ----
  // lane holds D[n][m]: n_local = wn + i*16 + q*4 + r, m_local = wm + j*16 + l.
  int lj[4];
#pragma unroll
  for (int j = 0; j < 4; ++j) lj[j] = labLDS[wm + j * 16 + l] - n0 - wn;
  bool hit = false;
#pragma unroll
  for (int j = 0; j < 4; ++j) hit = hit || ((unsigned)lj[j] < 64u);
  if (__any(hit)) {            // rare (~3% of blocks): mask positive column pre-max
#pragma unroll
    for (int j = 0; j < 4; ++j) {
      int relq = lj[j] - q * 4;
#pragma unroll
      for (int i = 0; i < 4; ++i) {
        int rel = relq - i * 16;
#pragma unroll
        for (int r = 0; r < 4; ++r)
          if (rel == r) acc[i][j][r] = -INFINITY;
      }
    }
  }
  // frag (i,j) covers exactly group g = wn/16 + i for 16 m's; reduce 4 regs in-lane,
  // then across q (lanes ^16, ^32) on RTZ-packed fp16 (monotone: max commutes with RTZ).
#pragma unroll
  for (int j = 0; j < 4; ++j) {
    float mx[4];
#pragma unroll
    for (int i = 0; i < 4; ++i)
      mx[i] = fmaxf(fmaxf(acc[i][j][0], acc[i][j][1]),
                    fmaxf(acc[i][j][2], acc[i][j][3]));
    union { f16x2 h; uint u; } c0, c1;
    c0.h = __builtin_amdgcn_cvt_pkrtz(mx[0], mx[1]);
    c1.h = __builtin_amdgcn_cvt_pkrtz(mx[2], mx[3]);
    uint u01 = c0.u, u23 = c1.u;
    u01 = hmax2(u01, __shfl_xor(u01, 16));
    u01 = hmax2(u01, __shfl_xor(u01, 32));
    u23 = hmax2(u23, __shfl_xor(u23, 16));
    u23 = hmax2(u23, __shfl_xor(u23, 32));
    if (q == 0) {
      uint2 w; w.x = u01; w.y = u23;
      *(uint2*)&gm[wm + j * 16 + l][wn >> 4] = w;
    }
  }
  __syncthreads();
  if (tid < 128) {
    uint4 w = *(const uint4*)&gm[tid][0];
    *(uint4*)(cand + ((size_t)(m0 + tid) * NTILES + bxTile) * 8) = w;
  }
}

// fp16-bit monotone key <-> value
__device__ __forceinline__ float dec_key(int k) {
  if (k < 0x0400) return -INFINITY;
  ushort h = (k >= 0x8000) ? (ushort)(k ^ 0x8000) : (ushort)(~k & 0xFFFF);
  __half_raw hr; hr.x = h;
  return __half2float((__half)hr);
}

// ---------------- per-row: top-50 of 4096 pool values via key bisection + loss ----------------
__global__ void final_select(const ushort* __restrict__ cand, const float* __restrict__ f,
                             const float* __restrict__ cen, const int* __restrict__ label,
                             float* __restrict__ rowloss) {
  __shared__ float sred[8];
  __shared__ int   sint[8];
  const int row = blockIdx.x, tid = threadIdx.x;
  const int lane = tid & 63, wid = tid >> 6;
  const int lab = label[row];

  float v[16];
  const uint4* p = (const uint4*)(cand + (size_t)row * (NTILES * 8));
#pragma unroll
  for (int g = 0; g < 2; ++g) {
    uint4 u = p[tid + g * 256];
    union { uint u; f16x2 h; } c;
    c.u = u.x; v[g * 8 + 0] = (float)c.h.x; v[g * 8 + 1] = (float)c.h.y;
    c.u = u.y; v[g * 8 + 2] = (float)c.h.x; v[g * 8 + 3] = (float)c.h.y;
    c.u = u.z; v[g * 8 + 4] = (float)c.h.x; v[g * 8 + 5] = (float)c.h.y;
    c.u = u.w; v[g * 8 + 6] = (float)c.h.x; v[g * 8 + 7] = (float)c.h.y;
  }
  float pv = f[(size_t)row * D_DIM + tid] * cen[(size_t)lab * D_DIM + tid];
  float m = -INFINITY;
#pragma unroll
  for (int k = 0; k < 16; ++k) m = fmaxf(m, v[k]);
#pragma unroll
  for (int o = 32; o > 0; o >>= 1) {
    m = fmaxf(m, __shfl_down(m, o));
    pv += __shfl_down(pv, o);
  }
  if (lane == 0) { sred[wid] = m; sred[4 + wid] = pv; }
  __syncthreads();
  m = fmaxf(fmaxf(sred[0], sred[1]), fmaxf(sred[2], sred[3]));
  const float pos = sred[4] + sred[5] + sred[6] + sred[7];

  // bisection seeded at the row max key: answer lies within ~300 keys; 2048 is ample
  __half hm = __float2half(m);
  int hb = (int)(*(ushort*)&hm);
  int km = (m >= 0.f) ? (0x8000 | hb) : (~hb & 0xFFFF);
  int lo = km - 2048, hi = km;
  if (lo < 0x0400) lo = 0x0400;
#pragma unroll
  for (int it = 0; it < 12; ++it) {
    int mid = (lo + hi) >> 1;
    float tau = dec_key(mid);
    int c = 0;
#pragma unroll
    for (int k = 0; k < 16; ++k) c += (v[k] > tau) ? 1 : 0;
#pragma unroll
    for (int o = 32; o > 0; o >>= 1) c += __shfl_down(c, o);
    if (lane == 0) sint[(it & 1) * 4 + wid] = c;
    __syncthreads();
    int base = (it & 1) * 4;
    int tot = sint[base] + sint[base + 1] + sint[base + 2] + sint[base + 3];
    if (tot <= 49) hi = mid; else lo = mid + 1;
  }

  const float tau = dec_key(hi);
  float sum = 0.f, se = 0.f; int c = 0;
#pragma unroll
  for (int k = 0; k < 16; ++k) {
    if (v[k] > tau) { ++c; sum += v[k]; se += expf(v[k] - m); }
  }
#pragma unroll
  for (int o = 32; o > 0; o >>= 1) {
    sum += __shfl_down(sum, o);
    se  += __shfl_down(se, o);
    c   += __shfl_down(c, o);
  }
  if (lane == 0) { sred[wid] = sum; sred[4 + wid] = se; sint[wid] = c; }
  __syncthreads();
  if (tid == 0) {
    float S = sred[0] + sred[1] + sred[2] + sred[3];
    float E = sred[4] + sred[5] + sred[6] + sred[7];
    int   C = sint[0] + sint[1] + sint[2] + sint[3];
    float nfill = (float)(N_NEG - C);
    S += nfill * tau;
    E += nfill * expf(tau - m);
    float M = fmaxf(m, pos);
    float seAll = E * expf(m - M) + expf(pos - M);
    float lse = M + logf(seAll);
    rowloss[row] = 0.9102f * lse - 0.9002f * pos - 2.0e-4f * S;
  }
}

__global__ void sum_loss(const float* __restrict__ rowloss, float* __restrict__ out) {
  __shared__ float red[4];
  const int tid = threadIdx.x;
  float s = 0.f;
  for (int i = tid; i < B_ROWS; i += 256) s += rowloss[i];
#pragma unroll
  for (int o = 32; o > 0; o >>= 1) s += __shfl_down(s, o);
  if ((tid & 63) == 0) red[tid >> 6] = s;
  __syncthreads();
  if (tid == 0) out[0] = (red[0] + red[1] + red[2] + red[3]) * (1.0f / B_ROWS);
}

extern "C" void kernel_launch(void* const* d_in, const int* in_sizes, int n_in,
                              void* d_out, int out_size, void* d_ws, size_t ws_size,
                              hipStream_t stream) {
  const float* f   = (const float*)d_in[0];
  const float* cen = (const float*)d_in[1];
  const int*   label = (const int*)d_in[2];
  float* out = (float*)d_out;

  char* ws = (char*)d_ws;
  ushort* cand    = (ushort*)ws;                      // 16 MiB: [2048][512][8] fp16
  ushort* fb      = (ushort*)(ws + 16777216);         // 1 MiB
  float*  rowloss = (float*)(ws + 17825792);          // 8 KiB

  cvt_swz<<<256, 256, 0, stream>>>(f, fb, (B_ROWS * D_DIM) / 8);

  dim3 grid(B_ROWS / 128, NTILES);  // XCD-chunk swizzled inside the kernel
  gemm_reduce<<<grid, 256, 0, stream>>>(fb, cen, label, cand);

  final_select<<<B_ROWS, 256, 0, stream>>>(cand, f, cen, label, rowloss);
  sum_loss<<<1, 256, 0, stream>>>(rowloss, out);
}

// Round 3
// 209.847 us; speedup vs baseline: 1.2712x; 1.2712x over previous
//
#include <hip/hip_runtime.h>
#include <hip/hip_fp16.h>

#define B_ROWS 2048
#define C_COLS 65536
#define D_DIM  256
#define N_NEG  50
#define NTILES (C_COLS / 128)   // 512 column tiles

typedef __attribute__((ext_vector_type(8))) short short8;
typedef __attribute__((ext_vector_type(4))) float floatx4;
typedef __fp16 f16x2 __attribute__((ext_vector_type(2)));

__device__ __forceinline__ ushort f2bf(float f) {
  unsigned u = __float_as_uint(f);
  unsigned r = (u + 0x7FFFu + ((u >> 16) & 1u)) >> 16;  // RNE
  return (ushort)r;
}

__device__ __forceinline__ uint hmax2(uint a, uint b) {
  union { uint u; f16x2 h; } x, y, r;
  x.u = a; y.u = b;
  r.h = __builtin_elementwise_max(x.h, y.h);
  return r.u;
}

// ---------------- fp32 -> bf16 convert, K-block XOR swizzle in global layout ----
__global__ void cvt_swz(const float* __restrict__ in, ushort* __restrict__ out, int n8) {
  int i = blockIdx.x * blockDim.x + threadIdx.x;
  if (i >= n8) return;
  int row = i >> 5;
  int ka  = i & 31;
  int ktile = ka >> 3, kb = ka & 7;
  const float4* src = (const float4*)(in + (size_t)i * 8);
  float4 a = src[0], b = src[1];
  ushort4 o0, o1;
  o0.x = f2bf(a.x); o0.y = f2bf(a.y); o0.z = f2bf(a.z); o0.w = f2bf(a.w);
  o1.x = f2bf(b.x); o1.y = f2bf(b.y); o1.z = f2bf(b.z); o1.w = f2bf(b.w);
  ushort* dst = out + (size_t)row * D_DIM + ktile * 64 + ((kb ^ (row & 7)) << 3);
  ((ushort4*)dst)[0] = o0;
  ((ushort4*)dst)[1] = o1;
}

__device__ __forceinline__ void async16(const void* g, void* l) {
  __builtin_amdgcn_global_load_lds((const __attribute__((address_space(1))) void*)g,
                                   (__attribute__((address_space(3))) void*)l,
                                   16, 0, 0);
}

// ---------------- GEMM (D[n][m]) + in-register 16:1 group-max reduction ----------------
// PREB=true: both operands bf16, staged via global_load_lds (the proven 79.6us core).
// XCD-chunk remap: each XCD owns 64 consecutive tiles x all 16 slabs, slab-fastest ->
// cb tile (64KB) stays in that XCD's L2 across its 16 uses.
// cand layout [tile][row][8] fp16: each block writes one contiguous 2KB burst
// (full 128B lines, written once -> no partial-line eviction amplification).
template <bool PREB>
__global__ void gemm_reduce(const ushort* __restrict__ fb,
                            const ushort* __restrict__ cb,
                            const float* __restrict__ cen,
                            const int* __restrict__ label,
                            ushort* __restrict__ cand) {
  __shared__ __align__(16) ushort Cs[128 * 64];   // cen bf16 [128][64], swizzled kblks
  __shared__ __align__(16) ushort Fs[128 * 64];   // f   bf16 [128][64], swizzled kblks
  __shared__ __align__(16) ushort gm[128][8];     // fp16 group-max [m][group]
  __shared__ int labLDS[128];

  const int tid = threadIdx.x, wave = tid >> 6, lane = tid & 63;
  const int l = lane & 15, q = lane >> 4;

  // bijective XCD-chunk remap (8192 blocks, 8 XCDs, 1024 each; slab-fastest inside)
  const int lin = blockIdx.y * 16 + blockIdx.x;
  const int lg  = (lin & 7) * 1024 + (lin >> 3);
  const int m0 = (lg & 15) << 7;
  const int bxTile = lg >> 4;
  const int n0 = bxTile << 7;
  if (tid < 128) labLDS[tid] = label[m0 + tid];

  floatx4 acc[4][4] = {};               // [i: n-block][j: m-block]
  const int wn = (wave >> 1) * 64, wm = (wave & 1) * 64;

  for (int kt = 0; kt < D_DIM / 64; ++kt) {
#pragma unroll
    for (int r = 0; r < 4; ++r) {
      int idx = r * 2048 + wave * 512 + lane * 8;
      int row = idx >> 6, kk = idx & 63;
      async16(fb + (size_t)(m0 + row) * D_DIM + kt * 64 + kk, Fs + r * 2048 + wave * 512);
      if (PREB)
        async16(cb + (size_t)(n0 + row) * D_DIM + kt * 64 + kk, Cs + r * 2048 + wave * 512);
    }
    if (!PREB) {
      // fallback: fused fp32 load -> bf16 RNE -> swizzled LDS store
      float4 ra[4], rb[4];
#pragma unroll
      for (int g = 0; g < 4; ++g) {
        int e = (tid + g * 256) * 8;
        const float* gp = cen + (size_t)(n0 + (e >> 6)) * D_DIM + kt * 64 + (e & 63);
        ra[g] = *(const float4*)gp;
        rb[g] = *(const float4*)(gp + 4);
      }
#pragma unroll
      for (int g = 0; g < 4; ++g) {
        int e = (tid + g * 256) * 8;
        int row = e >> 6, kblk = (e >> 3) & 7;
        uint4 o;
        o.x = (uint)f2bf(ra[g].x) | ((uint)f2bf(ra[g].y) << 16);
        o.y = (uint)f2bf(ra[g].z) | ((uint)f2bf(ra[g].w) << 16);
        o.z = (uint)f2bf(rb[g].x) | ((uint)f2bf(rb[g].y) << 16);
        o.w = (uint)f2bf(rb[g].z) | ((uint)f2bf(rb[g].w) << 16);
        *(uint4*)(Cs + (row << 6) + ((kblk ^ (row & 7)) << 3)) = o;
      }
    }
    __syncthreads();

#pragma unroll
    for (int ks = 0; ks < 2; ++ks) {
      short8 a[4], b[4];
#pragma unroll
      for (int i = 0; i < 4; ++i) {
        int swz = ((4 * ks + q) ^ (l & 7)) << 3;
        a[i] = *(const short8*)(Cs + ((wn + i * 16 + l) << 6) + swz);
        b[i] = *(const short8*)(Fs + ((wm + i * 16 + l) << 6) + swz);
      }
#pragma unroll
      for (int i = 0; i < 4; ++i)
#pragma unroll
        for (int j = 0; j < 4; ++j)
          acc[i][j] = __builtin_amdgcn_mfma_f32_16x16x32_bf16(a[i], b[j], acc[i][j], 0, 0, 0);
    }
    __syncthreads();
  }

  // ---- epilogue: in-register label mask + 16:1 group-max (verified round 2) ----
  // lane holds D[n][m]: n_local = wn + i*16 + q*4 + r, m_local = wm + j*16 + l.
  int lj[4];
#pragma unroll
  for (int j = 0; j < 4; ++j) lj[j] = labLDS[wm + j * 16 + l] - n0 - wn;
  bool hit = false;
#pragma unroll
  for (int j = 0; j < 4; ++j) hit = hit || ((unsigned)lj[j] < 64u);
  if (__any(hit)) {            // rare (~3% of blocks): mask positive column pre-max
#pragma unroll
    for (int j = 0; j < 4; ++j) {
      int relq = lj[j] - q * 4;
#pragma unroll
      for (int i = 0; i < 4; ++i) {
        int rel = relq - i * 16;
#pragma unroll
        for (int r = 0; r < 4; ++r)
          if (rel == r) acc[i][j][r] = -INFINITY;
      }
    }
  }
  // frag (i,j) covers exactly group g = wn/16 + i for 16 m's; reduce 4 regs in-lane,
  // then across q (lanes ^16, ^32) on RTZ-packed fp16 (monotone: max commutes with RTZ).
#pragma unroll
  for (int j = 0; j < 4; ++j) {
    float mx[4];
#pragma unroll
    for (int i = 0; i < 4; ++i)
      mx[i] = fmaxf(fmaxf(acc[i][j][0], acc[i][j][1]),
                    fmaxf(acc[i][j][2], acc[i][j][3]));
    union { f16x2 h; uint u; } c0, c1;
    c0.h = __builtin_amdgcn_cvt_pkrtz(mx[0], mx[1]);
    c1.h = __builtin_amdgcn_cvt_pkrtz(mx[2], mx[3]);
    uint u01 = c0.u, u23 = c1.u;
    u01 = hmax2(u01, __shfl_xor(u01, 16));
    u01 = hmax2(u01, __shfl_xor(u01, 32));
    u23 = hmax2(u23, __shfl_xor(u23, 16));
    u23 = hmax2(u23, __shfl_xor(u23, 32));
    if (q == 0) {
      uint2 w; w.x = u01; w.y = u23;
      *(uint2*)&gm[wm + j * 16 + l][wn >> 4] = w;
    }
  }
  __syncthreads();
  // [tile][row][8] fp16: 128 x 16B = contiguous 2KB burst per block, full lines.
  if (tid < 128) {
    uint4 w = *(const uint4*)&gm[tid][0];
    *(uint4*)(cand + ((size_t)bxTile * B_ROWS + (m0 + tid)) * 8) = w;
  }
}

// fp16-bit monotone key <-> value
__device__ __forceinline__ float dec_key(int k) {
  if (k < 0x0400) return -INFINITY;
  ushort h = (k >= 0x8000) ? (ushort)(k ^ 0x8000) : (ushort)(~k & 0xFFFF);
  __half_raw hr; hr.x = h;
  return __half2float((__half)hr);
}

// ---------------- per-row: top-50 of 4096 pool values via key bisection + loss ----------------
__global__ void final_select(const ushort* __restrict__ cand, const float* __restrict__ f,
                             const float* __restrict__ cen, const int* __restrict__ label,
                             float* __restrict__ rowloss) {
  __shared__ float sred[8];
  __shared__ int   sint[8];
  const int row = blockIdx.x, tid = threadIdx.x;
  const int lane = tid & 63, wid = tid >> 6;
  const int lab = label[row];

  float v[16];
  const uint4* p = (const uint4*)cand;   // uint4 = 8 fp16 groups of one (tile,row)
#pragma unroll
  for (int g = 0; g < 2; ++g) {
    uint4 u = p[(size_t)(tid + g * 256) * B_ROWS + row];
    union { uint u; f16x2 h; } c;
    c.u = u.x; v[g * 8 + 0] = (float)c.h.x; v[g * 8 + 1] = (float)c.h.y;
    c.u = u.y; v[g * 8 + 2] = (float)c.h.x; v[g * 8 + 3] = (float)c.h.y;
    c.u = u.z; v[g * 8 + 4] = (float)c.h.x; v[g * 8 + 5] = (float)c.h.y;
    c.u = u.w; v[g * 8 + 6] = (float)c.h.x; v[g * 8 + 7] = (float)c.h.y;
  }
  float pv = f[(size_t)row * D_DIM + tid] * cen[(size_t)lab * D_DIM + tid];
  float m = -INFINITY;
#pragma unroll
  for (int k = 0; k < 16; ++k) m = fmaxf(m, v[k]);
#pragma unroll
  for (int o = 32; o > 0; o >>= 1) {
    m = fmaxf(m, __shfl_down(m, o));
    pv += __shfl_down(pv, o);
  }
  if (lane == 0) { sred[wid] = m; sred[4 + wid] = pv; }
  __syncthreads();
  m = fmaxf(fmaxf(sred[0], sred[1]), fmaxf(sred[2], sred[3]));
  const float pos = sred[4] + sred[5] + sred[6] + sred[7];

  // bisection seeded at the row max key: answer lies within ~300 keys; 2048 is ample
  __half hm = __float2half(m);
  int hb = (int)(*(ushort*)&hm);
  int km = (m >= 0.f) ? (0x8000 | hb) : (~hb & 0xFFFF);
  int lo = km - 2048, hi = km;
  if (lo < 0x0400) lo = 0x0400;
#pragma unroll
  for (int it = 0; it < 12; ++it) {
    int mid = (lo + hi) >> 1;
    float tau = dec_key(mid);
    int c = 0;
#pragma unroll
    for (int k = 0; k < 16; ++k) c += (v[k] > tau) ? 1 : 0;
#pragma unroll
    for (int o = 32; o > 0; o >>= 1) c += __shfl_down(c, o);
    if (lane == 0) sint[(it & 1) * 4 + wid] = c;
    __syncthreads();
    int base = (it & 1) * 4;
    int tot = sint[base] + sint[base + 1] + sint[base + 2] + sint[base + 3];
    if (tot <= 49) hi = mid; else lo = mid + 1;
  }

  const float tau = dec_key(hi);
  float sum = 0.f, se = 0.f; int c = 0;
#pragma unroll
  for (int k = 0; k < 16; ++k) {
    if (v[k] > tau) { ++c; sum += v[k]; se += expf(v[k] - m); }
  }
#pragma unroll
  for (int o = 32; o > 0; o >>= 1) {
    sum += __shfl_down(sum, o);
    se  += __shfl_down(se, o);
    c   += __shfl_down(c, o);
  }
  if (lane == 0) { sred[wid] = sum; sred[4 + wid] = se; sint[wid] = c; }
  __syncthreads();
  if (tid == 0) {
    float S = sred[0] + sred[1] + sred[2] + sred[3];
    float E = sred[4] + sred[5] + sred[6] + sred[7];
    int   C = sint[0] + sint[1] + sint[2] + sint[3];
    float nfill = (float)(N_NEG - C);
    S += nfill * tau;
    E += nfill * expf(tau - m);
    float M = fmaxf(m, pos);
    float seAll = E * expf(m - M) + expf(pos - M);
    float lse = M + logf(seAll);
    rowloss[row] = 0.9102f * lse - 0.9002f * pos - 2.0e-4f * S;
  }
}

__global__ void sum_loss(const float* __restrict__ rowloss, float* __restrict__ out) {
  __shared__ float red[4];
  const int tid = threadIdx.x;
  float s = 0.f;
  for (int i = tid; i < B_ROWS; i += 256) s += rowloss[i];
#pragma unroll
  for (int o = 32; o > 0; o >>= 1) s += __shfl_down(s, o);
  if ((tid & 63) == 0) red[tid >> 6] = s;
  __syncthreads();
  if (tid == 0) out[0] = (red[0] + red[1] + red[2] + red[3]) * (1.0f / B_ROWS);
}

extern "C" void kernel_launch(void* const* d_in, const int* in_sizes, int n_in,
                              void* d_out, int out_size, void* d_ws, size_t ws_size,
                              hipStream_t stream) {
  const float* f   = (const float*)d_in[0];
  const float* cen = (const float*)d_in[1];
  const int*   label = (const int*)d_in[2];
  float* out = (float*)d_out;

  char* ws = (char*)d_ws;
  ushort* cand    = (ushort*)ws;                      // 16 MiB: [512 tiles][2048 rows][8] fp16
  ushort* fb      = (ushort*)(ws + 16777216);         // 1 MiB
  float*  rowloss = (float*)(ws + 17825792);          // 8 KiB
  ushort* cb      = (ushort*)(ws + 17833984);         // 32 MiB (fast path)
  const bool pre = ws_size >= (17833984ull + 33554432ull);

  cvt_swz<<<256, 256, 0, stream>>>(f, fb, (B_ROWS * D_DIM) / 8);

  dim3 grid(B_ROWS / 128, NTILES);  // XCD-chunk swizzled inside the kernel
  if (pre) {
    cvt_swz<<<8192, 256, 0, stream>>>(cen, cb, (C_COLS * D_DIM) / 8);
    gemm_reduce<true><<<grid, 256, 0, stream>>>(fb, cb, nullptr, label, cand);
  } else {
    gemm_reduce<false><<<grid, 256, 0, stream>>>(fb, nullptr, cen, label, cand);
  }

  final_select<<<B_ROWS, 256, 0, stream>>>(cand, f, cen, label, rowloss);
  sum_loss<<<1, 256, 0, stream>>>(rowloss, out);
}

// Round 4
// 190.067 us; speedup vs baseline: 1.4035x; 1.1041x over previous
//
#include <hip/hip_runtime.h>
#include <hip/hip_fp16.h>

#define B_ROWS 2048
#define C_COLS 65536
#define D_DIM  256
#define N_NEG  50
#define NTILES (C_COLS / 128)   // 512 column tiles

typedef __attribute__((ext_vector_type(8))) short short8;
typedef __attribute__((ext_vector_type(4))) float floatx4;
typedef __fp16 f16x2 __attribute__((ext_vector_type(2)));

__device__ __forceinline__ ushort f2bf(float f) {
  unsigned u = __float_as_uint(f);
  unsigned r = (u + 0x7FFFu + ((u >> 16) & 1u)) >> 16;  // RNE
  return (ushort)r;
}

__device__ __forceinline__ uint hmax2(uint a, uint b) {
  union { uint u; f16x2 h; } x, y, r;
  x.u = a; y.u = b;
  r.h = __builtin_elementwise_max(x.h, y.h);
  return r.u;
}

// ---------------- fp32 -> bf16 convert, K-block XOR swizzle in global layout ----
__global__ void cvt_swz(const float* __restrict__ in, ushort* __restrict__ out, int n8) {
  int i = blockIdx.x * blockDim.x + threadIdx.x;
  if (i >= n8) return;
  int row = i >> 5;
  int ka  = i & 31;
  int ktile = ka >> 3, kb = ka & 7;
  const float4* src = (const float4*)(in + (size_t)i * 8);
  float4 a = src[0], b = src[1];
  ushort4 o0, o1;
  o0.x = f2bf(a.x); o0.y = f2bf(a.y); o0.z = f2bf(a.z); o0.w = f2bf(a.w);
  o1.x = f2bf(b.x); o1.y = f2bf(b.y); o1.z = f2bf(b.z); o1.w = f2bf(b.w);
  ushort* dst = out + (size_t)row * D_DIM + ktile * 64 + ((kb ^ (row & 7)) << 3);
  ((ushort4*)dst)[0] = o0;
  ((ushort4*)dst)[1] = o1;
}

__device__ __forceinline__ void async16(const void* g, void* l) {
  __builtin_amdgcn_global_load_lds((const __attribute__((address_space(1))) void*)g,
                                   (__attribute__((address_space(3))) void*)l,
                                   16, 0, 0);
}

// ---------------- GEMM (D[n][m]) + in-register 16:1 group-max reduction ----------------
// (unchanged from round 3: 74us, MfmaUtil 38%, FETCH 20.6MB, WRITE 16.4MB, refcheck'd)
template <bool PREB>
__global__ void gemm_reduce(const ushort* __restrict__ fb,
                            const ushort* __restrict__ cb,
                            const float* __restrict__ cen,
                            const int* __restrict__ label,
                            ushort* __restrict__ cand) {
  __shared__ __align__(16) ushort Cs[128 * 64];   // cen bf16 [128][64], swizzled kblks
  __shared__ __align__(16) ushort Fs[128 * 64];   // f   bf16 [128][64], swizzled kblks
  __shared__ __align__(16) ushort gm[128][8];     // fp16 group-max [m][group]
  __shared__ int labLDS[128];

  const int tid = threadIdx.x, wave = tid >> 6, lane = tid & 63;
  const int l = lane & 15, q = lane >> 4;

  // bijective XCD-chunk remap (8192 blocks, 8 XCDs, 1024 each; slab-fastest inside)
  const int lin = blockIdx.y * 16 + blockIdx.x;
  const int lg  = (lin & 7) * 1024 + (lin >> 3);
  const int m0 = (lg & 15) << 7;
  const int bxTile = lg >> 4;
  const int n0 = bxTile << 7;
  if (tid < 128) labLDS[tid] = label[m0 + tid];

  floatx4 acc[4][4] = {};               // [i: n-block][j: m-block]
  const int wn = (wave >> 1) * 64, wm = (wave & 1) * 64;

  for (int kt = 0; kt < D_DIM / 64; ++kt) {
#pragma unroll
    for (int r = 0; r < 4; ++r) {
      int idx = r * 2048 + wave * 512 + lane * 8;
      int row = idx >> 6, kk = idx & 63;
      async16(fb + (size_t)(m0 + row) * D_DIM + kt * 64 + kk, Fs + r * 2048 + wave * 512);
      if (PREB)
        async16(cb + (size_t)(n0 + row) * D_DIM + kt * 64 + kk, Cs + r * 2048 + wave * 512);
    }
    if (!PREB) {
      float4 ra[4], rb[4];
#pragma unroll
      for (int g = 0; g < 4; ++g) {
        int e = (tid + g * 256) * 8;
        const float* gp = cen + (size_t)(n0 + (e >> 6)) * D_DIM + kt * 64 + (e & 63);
        ra[g] = *(const float4*)gp;
        rb[g] = *(const float4*)(gp + 4);
      }
#pragma unroll
      for (int g = 0; g < 4; ++g) {
        int e = (tid + g * 256) * 8;
        int row = e >> 6, kblk = (e >> 3) & 7;
        uint4 o;
        o.x = (uint)f2bf(ra[g].x) | ((uint)f2bf(ra[g].y) << 16);
        o.y = (uint)f2bf(ra[g].z) | ((uint)f2bf(ra[g].w) << 16);
        o.z = (uint)f2bf(rb[g].x) | ((uint)f2bf(rb[g].y) << 16);
        o.w = (uint)f2bf(rb[g].z) | ((uint)f2bf(rb[g].w) << 16);
        *(uint4*)(Cs + (row << 6) + ((kblk ^ (row & 7)) << 3)) = o;
      }
    }
    __syncthreads();

#pragma unroll
    for (int ks = 0; ks < 2; ++ks) {
      short8 a[4], b[4];
#pragma unroll
      for (int i = 0; i < 4; ++i) {
        int swz = ((4 * ks + q) ^ (l & 7)) << 3;
        a[i] = *(const short8*)(Cs + ((wn + i * 16 + l) << 6) + swz);
        b[i] = *(const short8*)(Fs + ((wm + i * 16 + l) << 6) + swz);
      }
#pragma unroll
      for (int i = 0; i < 4; ++i)
#pragma unroll
        for (int j = 0; j < 4; ++j)
          acc[i][j] = __builtin_amdgcn_mfma_f32_16x16x32_bf16(a[i], b[j], acc[i][j], 0, 0, 0);
    }
    __syncthreads();
  }

  // ---- epilogue: in-register label mask + 16:1 group-max ----
  int lj[4];
#pragma unroll
  for (int j = 0; j < 4; ++j) lj[j] = labLDS[wm + j * 16 + l] - n0 - wn;
  bool hit = false;
#pragma unroll
  for (int j = 0; j < 4; ++j) hit = hit || ((unsigned)lj[j] < 64u);
  if (__any(hit)) {
#pragma unroll
    for (int j = 0; j < 4; ++j) {
      int relq = lj[j] - q * 4;
#pragma unroll
      for (int i = 0; i < 4; ++i) {
        int rel = relq - i * 16;
#pragma unroll
        for (int r = 0; r < 4; ++r)
          if (rel == r) acc[i][j][r] = -INFINITY;
      }
    }
  }
#pragma unroll
  for (int j = 0; j < 4; ++j) {
    float mx[4];
#pragma unroll
    for (int i = 0; i < 4; ++i)
      mx[i] = fmaxf(fmaxf(acc[i][j][0], acc[i][j][1]),
                    fmaxf(acc[i][j][2], acc[i][j][3]));
    union { f16x2 h; uint u; } c0, c1;
    c0.h = __builtin_amdgcn_cvt_pkrtz(mx[0], mx[1]);
    c1.h = __builtin_amdgcn_cvt_pkrtz(mx[2], mx[3]);
    uint u01 = c0.u, u23 = c1.u;
    u01 = hmax2(u01, __shfl_xor(u01, 16));
    u01 = hmax2(u01, __shfl_xor(u01, 32));
    u23 = hmax2(u23, __shfl_xor(u23, 16));
    u23 = hmax2(u23, __shfl_xor(u23, 32));
    if (q == 0) {
      uint2 w; w.x = u01; w.y = u23;
      *(uint2*)&gm[wm + j * 16 + l][wn >> 4] = w;
    }
  }
  __syncthreads();
  // [tile][row][8] fp16: 128 x 16B = contiguous 2KB burst per block, full lines.
  if (tid < 128) {
    uint4 w = *(const uint4*)&gm[tid][0];
    *(uint4*)(cand + ((size_t)bxTile * B_ROWS + (m0 + tid)) * 8) = w;
  }
}

// fp16-bit monotone key <-> value
__device__ __forceinline__ float dec_key(int k) {
  if (k < 0x0400) return -INFINITY;
  ushort h = (k >= 0x8000) ? (ushort)(k ^ 0x8000) : (ushort)(~k & 0xFFFF);
  __half_raw hr; hr.x = h;
  return __half2float((__half)hr);
}

// ---------------- per-row top-50 + loss: ONE WAVE PER ROW, no barriers in bisection ----
// 256 blocks x 512 threads (8 waves = 8 consecutive rows). Cooperative 64KB LDS stage
// reads full 128B lines of the [tile][row] cand layout; each wave then owns 64 fp32
// values per lane (4096/row) and bisects with shfl_xor only.
__global__ __launch_bounds__(512) void final_select(const ushort* __restrict__ cand,
                                                    const float* __restrict__ f,
                                                    const float* __restrict__ cen,
                                                    const int* __restrict__ label,
                                                    float* __restrict__ rowloss) {
  __shared__ __align__(16) uint4 ST[NTILES][8];   // 64 KB, slot swizzled by tile&7
  const int tid = threadIdx.x;
  const int lane = tid & 63, w = tid >> 6;
  const int row0 = blockIdx.x * 8;

  const uint4* p = (const uint4*)cand;            // 1 uint4 = 8 fp16 groups of (tile,row)
#pragma unroll
  for (int k = 0; k < 8; ++k) {
    int j = k * 512 + tid;
    int tile = j >> 3, rr = j & 7;
    ST[tile][rr ^ (tile & 7)] = p[(size_t)tile * B_ROWS + row0 + rr];
  }
  __syncthreads();

  const int row = row0 + w;
  const int lab = label[row];

  // unpack this wave's row: lane holds tiles {c*64+lane}, 8 fp16 each -> 64 fp32
  float v[64];
#pragma unroll
  for (int c = 0; c < 8; ++c) {
    int tile = c * 64 + lane;
    uint4 u = ST[tile][w ^ (tile & 7)];
    union { uint u; f16x2 h; } cv;
    cv.u = u.x; v[c * 8 + 0] = (float)cv.h.x; v[c * 8 + 1] = (float)cv.h.y;
    cv.u = u.y; v[c * 8 + 2] = (float)cv.h.x; v[c * 8 + 3] = (float)cv.h.y;
    cv.u = u.z; v[c * 8 + 4] = (float)cv.h.x; v[c * 8 + 5] = (float)cv.h.y;
    cv.u = u.w; v[c * 8 + 6] = (float)cv.h.x; v[c * 8 + 7] = (float)cv.h.y;
  }

  // pos = f[row] . cen[lab] : 4 floats per lane
  float4 fv = *(const float4*)(f   + (size_t)row * D_DIM + lane * 4);
  float4 cv4 = *(const float4*)(cen + (size_t)lab * D_DIM + lane * 4);
  float pv = fv.x * cv4.x + fv.y * cv4.y + fv.z * cv4.z + fv.w * cv4.w;

  float m = v[0];
#pragma unroll
  for (int k = 1; k < 64; ++k) m = fmaxf(m, v[k]);
#pragma unroll
  for (int o = 32; o > 0; o >>= 1) {
    m = fmaxf(m, __shfl_xor(m, o));
    pv += __shfl_xor(pv, o);
  }
  const float pos = pv;

  // bisection seeded at the row max key: answer lies within ~300 keys; 2048 is ample
  __half hm = __float2half(m);
  int hb = (int)(*(ushort*)&hm);
  int km = (m >= 0.f) ? (0x8000 | hb) : (~hb & 0xFFFF);
  int lo = km - 2048, hi = km;
  if (lo < 0x0400) lo = 0x0400;
  for (int it = 0; it < 12; ++it) {
    int mid = (lo + hi) >> 1;
    float tau = dec_key(mid);
    int c = 0;
#pragma unroll
    for (int k = 0; k < 64; ++k) c += (v[k] > tau) ? 1 : 0;
#pragma unroll
    for (int o = 32; o > 0; o >>= 1) c += __shfl_xor(c, o);
    if (c <= 49) hi = mid; else lo = mid + 1;
  }

  const float tau = dec_key(hi);
  float sum = 0.f, se = 0.f; int c = 0;
#pragma unroll
  for (int k = 0; k < 64; ++k) {
    if (v[k] > tau) { ++c; sum += v[k]; se += expf(v[k] - m); }
  }
#pragma unroll
  for (int o = 32; o > 0; o >>= 1) {
    sum += __shfl_xor(sum, o);
    se  += __shfl_xor(se, o);
    c   += __shfl_xor(c, o);
  }
  if (lane == 0) {
    float nfill = (float)(N_NEG - c);
    float S = sum + nfill * tau;
    float E = se + nfill * expf(tau - m);
    float M = fmaxf(m, pos);
    float seAll = E * expf(m - M) + expf(pos - M);
    float lse = M + logf(seAll);
    rowloss[row] = 0.9102f * lse - 0.9002f * pos - 2.0e-4f * S;
  }
}

__global__ void sum_loss(const float* __restrict__ rowloss, float* __restrict__ out) {
  __shared__ float red[4];
  const int tid = threadIdx.x;
  float s = 0.f;
  for (int i = tid; i < B_ROWS; i += 256) s += rowloss[i];
#pragma unroll
  for (int o = 32; o > 0; o >>= 1) s += __shfl_down(s, o);
  if ((tid & 63) == 0) red[tid >> 6] = s;
  __syncthreads();
  if (tid == 0) out[0] = (red[0] + red[1] + red[2] + red[3]) * (1.0f / B_ROWS);
}

extern "C" void kernel_launch(void* const* d_in, const int* in_sizes, int n_in,
                              void* d_out, int out_size, void* d_ws, size_t ws_size,
                              hipStream_t stream) {
  const float* f   = (const float*)d_in[0];
  const float* cen = (const float*)d_in[1];
  const int*   label = (const int*)d_in[2];
  float* out = (float*)d_out;

  char* ws = (char*)d_ws;
  ushort* cand    = (ushort*)ws;                      // 16 MiB: [512 tiles][2048 rows][8] fp16
  ushort* fb      = (ushort*)(ws + 16777216);         // 1 MiB
  float*  rowloss = (float*)(ws + 17825792);          // 8 KiB
  ushort* cb      = (ushort*)(ws + 17833984);         // 32 MiB (fast path)
  const bool pre = ws_size >= (17833984ull + 33554432ull);

  cvt_swz<<<256, 256, 0, stream>>>(f, fb, (B_ROWS * D_DIM) / 8);

  dim3 grid(B_ROWS / 128, NTILES);  // XCD-chunk swizzled inside the kernel
  if (pre) {
    cvt_swz<<<8192, 256, 0, stream>>>(cen, cb, (C_COLS * D_DIM) / 8);
    gemm_reduce<true><<<grid, 256, 0, stream>>>(fb, cb, nullptr, label, cand);
  } else {
    gemm_reduce<false><<<grid, 256, 0, stream>>>(fb, nullptr, cen, label, cand);
  }

  final_select<<<B_ROWS / 8, 512, 0, stream>>>(cand, f, cen, label, rowloss);
  sum_loss<<<1, 256, 0, stream>>>(rowloss, out);
}